// Round 15
// baseline (188.971 us; speedup 1.0000x reference)
//
#include <hip/hip_runtime.h>
#include <hip/hip_fp16.h>

#define N_NODES 50000
#define N_EDGES 800000
#define IN_DIM 128
#define OUT_DIM 64
#define OUT_DATA 32

#define BUCKET_SHIFT 6
#define BUCKET_SIZE 64                                       // nodes per bucket
#define NBUCK ((N_NODES + BUCKET_SIZE - 1) / BUCKET_SIZE)    // 782
#define NBLK_BIN 128
#define BIN_THREADS 1024
#define EPB ((N_EDGES + NBLK_BIN - 1) / NBLK_BIN)            // 6250
#define ELCAP 1536                                           // bucket edge capacity (mean 1024)

// ---------------- workspace layout (bytes) ----------------
#define OFF_GCNT    0u          // int[NBUCK]       -> pad 4096  (zeroed)
#define OFF_GBASE   4096u       // int[NBUCK+1]     -> pad 4096
#define OFF_DEG     8192u       // int[50048]       -> pad 200704 (written by sortK)
#define OFF_NSTART  208896u     // int[50048]       -> pad 200704 (written by sortK)
#define OFF_PERBLK  409600u     // int[128*782]     -> pad 401408
#define OFF_EREC    811008u     // int[E] packed (local<<16)|src = 3.2 MB
#define OFF_EREC2   4012032u    // int[E] node-grouped           = 3.2 MB
#define OFF_XW      7213056u    // half[N*64] prescaled by dinv  = 6.4 MB
#define OFF_XW2     13613056u   // half[N*64] prescaled by dinv
#define OFF_WC      20013056u   // float[64*32]
#define OFF_BC      20021248u   // float[32]
// total ~20 MB

// Detect whether edge_index is stored as int64 (high dwords all zero) or int32.
__device__ __forceinline__ bool ei_is64(const int* ei) {
    int o = 0;
#pragma unroll
    for (int k = 0; k < 16; ++k) o |= ei[2 * k + 1];
    return o == 0;
}
__device__ __forceinline__ int load_ei(const int* ei, long long flat, bool is64) {
    return is64 ? (int)(((const long long*)ei)[flat]) : ei[flat];
}

// ---------------- zero gcnt (4096 B = 256 int4) ----------------
__global__ void zero_kernel(int4* __restrict__ p) {
    p[threadIdx.x] = make_int4(0, 0, 0, 0);
}

// ---------------- pass 1: bucket histogram (per-block LDS) ----------------
__global__ __launch_bounds__(BIN_THREADS) void hist_kernel(const int* __restrict__ ei,
                                                           int* __restrict__ gcnt,
                                                           int* __restrict__ perblk) {
    __shared__ int lh[NBUCK];
    int t = threadIdx.x;
    for (int i = t; i < NBUCK; i += BIN_THREADS) lh[i] = 0;
    __syncthreads();
    bool is64 = ei_is64(ei);
    int e0 = blockIdx.x * EPB;
    int e1 = e0 + EPB; if (e1 > N_EDGES) e1 = N_EDGES;
    for (int e = e0 + t; e < e1; e += BIN_THREADS) {
        int d = load_ei(ei, (long long)N_EDGES + e, is64);
        atomicAdd(&lh[d >> BUCKET_SHIFT], 1);
    }
    __syncthreads();
    for (int i = t; i < NBUCK; i += BIN_THREADS)
        perblk[blockIdx.x * NBUCK + i] = atomicAdd(&gcnt[i], lh[i]);
}

// ---------------- prefix over buckets; fused head-weight folding ----------------
__global__ __launch_bounds__(1024) void scanP_kernel(
    const int* __restrict__ gcnt, int* __restrict__ gbase,
    const float* __restrict__ Wp1, const float* __restrict__ bp1,
    const float* __restrict__ Wp2, const float* __restrict__ bp2,
    float* __restrict__ Wc, float* __restrict__ bc) {
    __shared__ int tmp[1024];
    int t = threadIdx.x;
    int v = (t < NBUCK) ? gcnt[t] : 0;
    tmp[t] = v;
    __syncthreads();
    for (int o = 1; o < 1024; o <<= 1) {
        int x = tmp[t];
        if (t >= o) x += tmp[t - o];
        __syncthreads();
        tmp[t] = x;
        __syncthreads();
    }
    if (t < NBUCK) gbase[t] = tmp[t] - v;
    if (t == NBUCK - 1) gbase[NBUCK] = tmp[t];
    // head fold: Wc = Wp1@Wp2, bc = bp1@Wp2+bp2
    for (int idx = t; idx < 64 * 32; idx += 1024) {
        int r = idx >> 5, j = idx & 31;
        float s = 0.0f;
        for (int k = 0; k < 64; ++k) s += Wp1[r * 64 + k] * Wp2[k * 32 + j];
        Wc[idx] = s;
    }
    if (t < 32) {
        float s = bp2[t];
        for (int k = 0; k < 64; ++k) s += bp1[k] * Wp2[k * 32 + t];
        bc[t] = s;
    }
}

// ---------------- pass 2: scatter packed records grouped by (block,bucket) ----------------
__global__ __launch_bounds__(BIN_THREADS) void scat_kernel(const int* __restrict__ ei,
                                                           const int* __restrict__ gbase,
                                                           const int* __restrict__ perblk,
                                                           int* __restrict__ erec) {
    __shared__ int lh[NBUCK];
    __shared__ int base[NBUCK];
    int t = threadIdx.x;
    for (int i = t; i < NBUCK; i += BIN_THREADS) {
        lh[i] = 0;
        base[i] = gbase[i] + perblk[blockIdx.x * NBUCK + i];
    }
    __syncthreads();
    bool is64 = ei_is64(ei);
    int e0 = blockIdx.x * EPB;
    int e1 = e0 + EPB; if (e1 > N_EDGES) e1 = N_EDGES;
    for (int e = e0 + t; e < e1; e += BIN_THREADS) {
        int s = load_ei(ei, e, is64);
        int d = load_ei(ei, (long long)N_EDGES + e, is64);
        int b = d >> BUCKET_SHIFT;
        int slot = atomicAdd(&lh[b], 1);
        erec[base[b] + slot] = s | ((d & (BUCKET_SIZE - 1)) << 16);  // s<65536, local<64
    }
}

// ---------------- one-time in-bucket counting sort: erec -> node-grouped erec2 ----------------
__global__ __launch_bounds__(512) void sortK_kernel(const int* __restrict__ erec,
                                                    const int* __restrict__ gbase,
                                                    int* __restrict__ erec2,
                                                    int* __restrict__ nodeStart,
                                                    int* __restrict__ deg) {
    __shared__ int elist[ELCAP];
    __shared__ int lcntS[64];
    __shared__ int startS[65];
    int t = threadIdx.x;
    int ebeg = gbase[blockIdx.x], eend = gbase[blockIdx.x + 1];
    int ecnt = eend - ebeg; if (ecnt > ELCAP) ecnt = ELCAP;
    for (int i = t; i < ecnt; i += 512) elist[i] = erec[ebeg + i];
    if (t < 64) lcntS[t] = 0;
    __syncthreads();
    int rec0 = -1, rank0 = 0, rec1 = -1, rank1 = 0, rec2 = -1, rank2 = 0;
    { int i = t;        if (i < ecnt) { rec0 = elist[i]; rank0 = atomicAdd(&lcntS[rec0 >> 16], 1); } }
    { int i = t + 512;  if (i < ecnt) { rec1 = elist[i]; rank1 = atomicAdd(&lcntS[rec1 >> 16], 1); } }
    { int i = t + 1024; if (i < ecnt) { rec2 = elist[i]; rank2 = atomicAdd(&lcntS[rec2 >> 16], 1); } }
    __syncthreads();
    if (t < 64) {
        int vcnt = lcntS[t]; int sum = vcnt;
        for (int off = 1; off < 64; off <<= 1) {
            int o = __shfl_up(sum, off, 64);
            if (t >= off) sum += o;
        }
        startS[t + 1] = sum; if (t == 0) startS[0] = 0;
    }
    __syncthreads();
    if (rec0 >= 0) erec2[ebeg + startS[rec0 >> 16] + rank0] = rec0;
    if (rec1 >= 0) erec2[ebeg + startS[rec1 >> 16] + rank1] = rec1;
    if (rec2 >= 0) erec2[ebeg + startS[rec2 >> 16] + rank2] = rec2;
    if (t < 64) {
        int node = (blockIdx.x << BUCKET_SHIFT) + t;
        nodeStart[node] = ebeg + startS[t];
        deg[node] = startS[t + 1] - startS[t];
    }
}

// ---------------- dense GEMM: wave=row, lane=col, W in registers ----------------
// Yh[row][lane] = (sum_k x[row][k] * W[k][lane]) * dinv[row], fp16 out.
// x[row][k] is wave-uniform (scalar path); W column lives in 128 VGPRs/lane;
// no LDS, no occupancy dependence. 782 waves cover 50000 rows (64 rows/wave).
__global__ __launch_bounds__(256) void gemmV_kernel(const float* __restrict__ X,
                                                    const float* __restrict__ W,
                                                    const int* __restrict__ deg,
                                                    __half* __restrict__ Yh) {
    int t = threadIdx.x, lane = t & 63;
    float wreg[IN_DIM];
#pragma unroll
    for (int k = 0; k < IN_DIM; ++k) wreg[k] = W[k * 64 + lane];
    int wid = __builtin_amdgcn_readfirstlane(blockIdx.x * 4 + (t >> 6));
    int r0 = wid * 64;
    for (int i = 0; i < 64; ++i) {
        int row = r0 + i;
        if (row >= N_NODES) break;             // wave-uniform branch
        const float* xr = X + (size_t)row * IN_DIM;   // uniform address -> scalar loads
        float a0 = 0.0f, a1 = 0.0f, a2 = 0.0f, a3 = 0.0f;
#pragma unroll
        for (int k = 0; k < IN_DIM; k += 4) {
            a0 = fmaf(xr[k + 0], wreg[k + 0], a0);
            a1 = fmaf(xr[k + 1], wreg[k + 1], a1);
            a2 = fmaf(xr[k + 2], wreg[k + 2], a2);
            a3 = fmaf(xr[k + 3], wreg[k + 3], a3);
        }
        float acc = (a0 + a1) + (a2 + a3);
        float di = rsqrtf((float)deg[row] + 1.0f);
        Yh[(size_t)row * 64 + lane] = __float2half_rn(acc * di);
    }
}

// ---------------- per-node register gather, 16 rows in flight ----------------
__device__ __forceinline__ float gatherN(const __half* __restrict__ xwp,
                                         const int* __restrict__ er,
                                         int s0, int n, int lane) {
    float acc = 0.0f;
    int e = 0;
    for (; e + 16 <= n; e += 16) {
        int r[16]; float v[16];
#pragma unroll
        for (int k = 0; k < 16; ++k) r[k] = er[s0 + e + k];
#pragma unroll
        for (int k = 0; k < 16; ++k) v[k] = __half2float(xwp[((r[k] & 0xFFFF) << 6) + lane]);
#pragma unroll
        for (int k = 0; k < 16; ++k) acc += v[k];
    }
    if (e + 8 <= n) {
        int r[8]; float v[8];
#pragma unroll
        for (int k = 0; k < 8; ++k) r[k] = er[s0 + e + k];
#pragma unroll
        for (int k = 0; k < 8; ++k) v[k] = __half2float(xwp[((r[k] & 0xFFFF) << 6) + lane]);
#pragma unroll
        for (int k = 0; k < 8; ++k) acc += v[k];
        e += 8;
    }
    if (e + 4 <= n) {
        int r[4]; float v[4];
#pragma unroll
        for (int k = 0; k < 4; ++k) r[k] = er[s0 + e + k];
#pragma unroll
        for (int k = 0; k < 4; ++k) v[k] = __half2float(xwp[((r[k] & 0xFFFF) << 6) + lane]);
#pragma unroll
        for (int k = 0; k < 4; ++k) acc += v[k];
        e += 4;
    }
    for (; e < n; ++e)
        acc += __half2float(xwp[((er[s0 + e] & 0xFFFF) << 6) + lane]);
    return acc;
}

// ---------------- layer1: per-node agg + tanh + @W2, writes prescaled fp16 xw2 ----------------
__global__ __launch_bounds__(256) void aggA_kernel(
    const __half* __restrict__ xwp, const int* __restrict__ erec2,
    const int* __restrict__ nodeStart, const int* __restrict__ deg,
    const float* __restrict__ b1v, const float* __restrict__ W2,
    __half* __restrict__ xw2p) {
    __shared__ float W2l[64 * 64];             // 16 KB
    __shared__ float rowS[4][64];
    int t = threadIdx.x;
    for (int i = t; i < 1024; i += 256)
        reinterpret_cast<float4*>(W2l)[i] = reinterpret_cast<const float4*>(W2)[i];
    __syncthreads();
    int node = __builtin_amdgcn_readfirstlane(blockIdx.x * 4 + (t >> 6));
    if (node >= N_NODES) return;
    int lane = t & 63, wib = t >> 6;
    int s0 = __builtin_amdgcn_readfirstlane(nodeStart[node]);
    int n  = __builtin_amdgcn_readfirstlane(deg[node]);
    float acc = gatherN(xwp, erec2, s0, n, lane);
    float selfv = __half2float(xwp[(node << 6) + lane]);
    float di = rsqrtf((float)n + 1.0f);
    float h = tanhf((acc + selfv) * di + b1v[lane]);
    rowS[wib][lane] = h;                       // wave-private
    float o = 0.0f;
#pragma unroll
    for (int f4 = 0; f4 < 16; ++f4) {
        float4 rv = reinterpret_cast<const float4*>(&rowS[wib][0])[f4];
        o += rv.x * W2l[(f4 * 4 + 0) * 64 + lane];
        o += rv.y * W2l[(f4 * 4 + 1) * 64 + lane];
        o += rv.z * W2l[(f4 * 4 + 2) * 64 + lane];
        o += rv.w * W2l[(f4 * 4 + 3) * 64 + lane];
    }
    xw2p[(node << 6) + lane] = __float2half_rn(o * di);   // prescale for layer 2
}

// ---------------- layer2: per-node agg + emb + tanh + head + log_softmax ----------------
__global__ __launch_bounds__(256) void aggB_kernel(
    const __half* __restrict__ xw2p, const int* __restrict__ erec2,
    const int* __restrict__ nodeStart, const int* __restrict__ deg,
    const float* __restrict__ b2v, const float* __restrict__ Wc,
    const float* __restrict__ bc, float* __restrict__ embOut,
    float* __restrict__ logitsOut) {
    __shared__ float Wcl[64 * 32];             // 8 KB
    __shared__ float rowS[4][64];
    __shared__ float bcl[32];
    int t = threadIdx.x;
    for (int i = t; i < 512; i += 256)
        reinterpret_cast<float4*>(Wcl)[i] = reinterpret_cast<const float4*>(Wc)[i];
    if (t < 32) bcl[t] = bc[t];
    __syncthreads();
    int node = __builtin_amdgcn_readfirstlane(blockIdx.x * 4 + (t >> 6));
    if (node >= N_NODES) return;
    int lane = t & 63, wib = t >> 6;
    int s0 = __builtin_amdgcn_readfirstlane(nodeStart[node]);
    int n  = __builtin_amdgcn_readfirstlane(deg[node]);
    float acc = gatherN(xw2p, erec2, s0, n, lane);
    float selfv = __half2float(xw2p[(node << 6) + lane]);
    float di = rsqrtf((float)n + 1.0f);
    float v = (acc + selfv) * di + b2v[lane];
    embOut[(node << 6) + lane] = v;
    rowS[wib][lane] = tanhf(v);                // wave-private
    int j = lane & 31, half = lane >> 5;
    float p = half ? 0.0f : bcl[j];
#pragma unroll
    for (int f4 = 0; f4 < 8; ++f4) {
        float4 rv = reinterpret_cast<const float4*>(&rowS[wib][half * 32])[f4];
        int fb = half * 32 + f4 * 4;
        p += rv.x * Wcl[(fb + 0) * 32 + j];
        p += rv.y * Wcl[(fb + 1) * 32 + j];
        p += rv.z * Wcl[(fb + 2) * 32 + j];
        p += rv.w * Wcl[(fb + 3) * 32 + j];
    }
    p += __shfl_down(p, 32);                   // lanes 0..31 hold full logits
    float m = p;
#pragma unroll
    for (int o = 16; o > 0; o >>= 1) m = fmaxf(m, __shfl_xor(m, o, 32));
    float ex = __expf(p - m);
    float s = ex;
#pragma unroll
    for (int o = 16; o > 0; o >>= 1) s += __shfl_xor(s, o, 32);
    if (half == 0) logitsOut[node * 32 + j] = p - m - logf(s);
}

extern "C" void kernel_launch(void* const* d_in, const int* in_sizes, int n_in,
                              void* d_out, int out_size, void* d_ws, size_t ws_size,
                              hipStream_t stream) {
    const float* x   = (const float*)d_in[0];
    const int*   ei  = (const int*)d_in[1];
    const float* W1  = (const float*)d_in[2];
    const float* b1  = (const float*)d_in[3];
    const float* W2  = (const float*)d_in[4];
    const float* b2  = (const float*)d_in[5];
    const float* Wp1 = (const float*)d_in[6];
    const float* bp1 = (const float*)d_in[7];
    const float* Wp2 = (const float*)d_in[8];
    const float* bp2 = (const float*)d_in[9];

    char* ws = (char*)d_ws;
    int*    gcnt   = (int*)(ws + OFF_GCNT);
    int*    gbase  = (int*)(ws + OFF_GBASE);
    int*    deg    = (int*)(ws + OFF_DEG);
    int*    nstart = (int*)(ws + OFF_NSTART);
    int*    perblk = (int*)(ws + OFF_PERBLK);
    int*    erec   = (int*)(ws + OFF_EREC);
    int*    erec2  = (int*)(ws + OFF_EREC2);
    __half* xwp    = (__half*)(ws + OFF_XW);
    __half* xw2p   = (__half*)(ws + OFF_XW2);
    float*  Wc     = (float*)(ws + OFF_WC);
    float*  bc     = (float*)(ws + OFF_BC);

    float* emb_out    = (float*)d_out;                        // [N,64]
    float* logits_out = (float*)d_out + (size_t)N_NODES * 64; // [N,32]

    zero_kernel<<<1, 256, 0, stream>>>((int4*)(ws + OFF_GCNT));
    hist_kernel<<<NBLK_BIN, BIN_THREADS, 0, stream>>>(ei, gcnt, perblk);
    scanP_kernel<<<1, 1024, 0, stream>>>(gcnt, gbase, Wp1, bp1, Wp2, bp2, Wc, bc);
    scat_kernel<<<NBLK_BIN, BIN_THREADS, 0, stream>>>(ei, gbase, perblk, erec);
    sortK_kernel<<<NBUCK, 512, 0, stream>>>(erec, gbase, erec2, nstart, deg);

    gemmV_kernel<<<(NBUCK + 3) / 4, 256, 0, stream>>>(x, W1, deg, xwp);
    aggA_kernel<<<(N_NODES + 3) / 4, 256, 0, stream>>>(xwp, erec2, nstart, deg, b1, W2, xw2p);
    aggB_kernel<<<(N_NODES + 3) / 4, 256, 0, stream>>>(xw2p, erec2, nstart, deg, b2, Wc, bc, emb_out, logits_out);
}

// Round 17
// 148.384 us; speedup vs baseline: 1.2735x; 1.2735x over previous
//
#include <hip/hip_runtime.h>
#include <hip/hip_fp16.h>

#define N_NODES 50000
#define N_EDGES 800000
#define IN_DIM 128
#define OUT_DIM 64
#define OUT_DATA 32

#define BUCKET_SHIFT 6
#define BUCKET_SIZE 64                                       // nodes per bucket
#define NBUCK ((N_NODES + BUCKET_SIZE - 1) / BUCKET_SIZE)    // 782
#define NBLK_BIN 128
#define BIN_THREADS 1024
#define EPB ((N_EDGES + NBLK_BIN - 1) / NBLK_BIN)            // 6250
#define ELCAP 1536                                           // bucket edge capacity (mean 1024)

// ---------------- workspace layout (bytes) ----------------
#define OFF_GCNT    0u          // int[NBUCK]       -> pad 4096  (zeroed)
#define OFF_GBASE   4096u       // int[NBUCK+1]     -> pad 4096
#define OFF_DEG     8192u       // int[50048]       -> pad 200704 (written by sortK)
#define OFF_NSTART  208896u     // int[50048]       -> pad 200704 (written by sortK)
#define OFF_PERBLK  409600u     // int[128*782]     -> pad 401408
#define OFF_EREC    811008u     // int[E] packed (local<<16)|src = 3.2 MB
#define OFF_EREC2   4012032u    // int[E] node-grouped           = 3.2 MB
#define OFF_XW      7213056u    // half[N*64] prescaled by dinv  = 6.4 MB
#define OFF_XW2     13613056u   // half[N*64] prescaled by dinv
#define OFF_WC      20013056u   // float[64*32]
#define OFF_BC      20021248u   // float[32]
// total ~20 MB

// Detect whether edge_index is stored as int64 (high dwords all zero) or int32.
__device__ __forceinline__ bool ei_is64(const int* ei) {
    int o = 0;
#pragma unroll
    for (int k = 0; k < 16; ++k) o |= ei[2 * k + 1];
    return o == 0;
}
__device__ __forceinline__ int load_ei(const int* ei, long long flat, bool is64) {
    return is64 ? (int)(((const long long*)ei)[flat]) : ei[flat];
}

// ---------------- zero gcnt (4096 B = 256 int4) ----------------
__global__ void zero_kernel(int4* __restrict__ p) {
    p[threadIdx.x] = make_int4(0, 0, 0, 0);
}

// ---------------- pass 1: bucket histogram (per-block LDS) ----------------
__global__ __launch_bounds__(BIN_THREADS) void hist_kernel(const int* __restrict__ ei,
                                                           int* __restrict__ gcnt,
                                                           int* __restrict__ perblk) {
    __shared__ int lh[NBUCK];
    int t = threadIdx.x;
    for (int i = t; i < NBUCK; i += BIN_THREADS) lh[i] = 0;
    __syncthreads();
    bool is64 = ei_is64(ei);
    int e0 = blockIdx.x * EPB;
    int e1 = e0 + EPB; if (e1 > N_EDGES) e1 = N_EDGES;
    for (int e = e0 + t; e < e1; e += BIN_THREADS) {
        int d = load_ei(ei, (long long)N_EDGES + e, is64);
        atomicAdd(&lh[d >> BUCKET_SHIFT], 1);
    }
    __syncthreads();
    for (int i = t; i < NBUCK; i += BIN_THREADS)
        perblk[blockIdx.x * NBUCK + i] = atomicAdd(&gcnt[i], lh[i]);
}

// ---------------- prefix over buckets; fused head-weight folding ----------------
__global__ __launch_bounds__(1024) void scanP_kernel(
    const int* __restrict__ gcnt, int* __restrict__ gbase,
    const float* __restrict__ Wp1, const float* __restrict__ bp1,
    const float* __restrict__ Wp2, const float* __restrict__ bp2,
    float* __restrict__ Wc, float* __restrict__ bc) {
    __shared__ int tmp[1024];
    int t = threadIdx.x;
    int v = (t < NBUCK) ? gcnt[t] : 0;
    tmp[t] = v;
    __syncthreads();
    for (int o = 1; o < 1024; o <<= 1) {
        int x = tmp[t];
        if (t >= o) x += tmp[t - o];
        __syncthreads();
        tmp[t] = x;
        __syncthreads();
    }
    if (t < NBUCK) gbase[t] = tmp[t] - v;
    if (t == NBUCK - 1) gbase[NBUCK] = tmp[t];
    // head fold: Wc = Wp1@Wp2, bc = bp1@Wp2+bp2
    for (int idx = t; idx < 64 * 32; idx += 1024) {
        int r = idx >> 5, j = idx & 31;
        float s = 0.0f;
        for (int k = 0; k < 64; ++k) s += Wp1[r * 64 + k] * Wp2[k * 32 + j];
        Wc[idx] = s;
    }
    if (t < 32) {
        float s = bp2[t];
        for (int k = 0; k < 64; ++k) s += bp1[k] * Wp2[k * 32 + t];
        bc[t] = s;
    }
}

// ---------------- pass 2: scatter packed records grouped by (block,bucket) ----------------
__global__ __launch_bounds__(BIN_THREADS) void scat_kernel(const int* __restrict__ ei,
                                                           const int* __restrict__ gbase,
                                                           const int* __restrict__ perblk,
                                                           int* __restrict__ erec) {
    __shared__ int lh[NBUCK];
    __shared__ int base[NBUCK];
    int t = threadIdx.x;
    for (int i = t; i < NBUCK; i += BIN_THREADS) {
        lh[i] = 0;
        base[i] = gbase[i] + perblk[blockIdx.x * NBUCK + i];
    }
    __syncthreads();
    bool is64 = ei_is64(ei);
    int e0 = blockIdx.x * EPB;
    int e1 = e0 + EPB; if (e1 > N_EDGES) e1 = N_EDGES;
    for (int e = e0 + t; e < e1; e += BIN_THREADS) {
        int s = load_ei(ei, e, is64);
        int d = load_ei(ei, (long long)N_EDGES + e, is64);
        int b = d >> BUCKET_SHIFT;
        int slot = atomicAdd(&lh[b], 1);
        erec[base[b] + slot] = s | ((d & (BUCKET_SIZE - 1)) << 16);  // s<65536, local<64
    }
}

// ---------------- one-time in-bucket counting sort: erec -> node-grouped erec2 ----------------
__global__ __launch_bounds__(512) void sortK_kernel(const int* __restrict__ erec,
                                                    const int* __restrict__ gbase,
                                                    int* __restrict__ erec2,
                                                    int* __restrict__ nodeStart,
                                                    int* __restrict__ deg) {
    __shared__ int elist[ELCAP];
    __shared__ int lcntS[64];
    __shared__ int startS[65];
    int t = threadIdx.x;
    int ebeg = gbase[blockIdx.x], eend = gbase[blockIdx.x + 1];
    int ecnt = eend - ebeg; if (ecnt > ELCAP) ecnt = ELCAP;
    for (int i = t; i < ecnt; i += 512) elist[i] = erec[ebeg + i];
    if (t < 64) lcntS[t] = 0;
    __syncthreads();
    int rec0 = -1, rank0 = 0, rec1 = -1, rank1 = 0, rec2 = -1, rank2 = 0;
    { int i = t;        if (i < ecnt) { rec0 = elist[i]; rank0 = atomicAdd(&lcntS[rec0 >> 16], 1); } }
    { int i = t + 512;  if (i < ecnt) { rec1 = elist[i]; rank1 = atomicAdd(&lcntS[rec1 >> 16], 1); } }
    { int i = t + 1024; if (i < ecnt) { rec2 = elist[i]; rank2 = atomicAdd(&lcntS[rec2 >> 16], 1); } }
    __syncthreads();
    if (t < 64) {
        int vcnt = lcntS[t]; int sum = vcnt;
        for (int off = 1; off < 64; off <<= 1) {
            int o = __shfl_up(sum, off, 64);
            if (t >= off) sum += o;
        }
        startS[t + 1] = sum; if (t == 0) startS[0] = 0;
    }
    __syncthreads();
    if (rec0 >= 0) erec2[ebeg + startS[rec0 >> 16] + rank0] = rec0;
    if (rec1 >= 0) erec2[ebeg + startS[rec1 >> 16] + rank1] = rec1;
    if (rec2 >= 0) erec2[ebeg + startS[rec2 >> 16] + rank2] = rec2;
    if (t < 64) {
        int node = (blockIdx.x << BUCKET_SHIFT) + t;
        nodeStart[node] = ebeg + startS[t];
        deg[node] = startS[t + 1] - startS[t];
    }
}

// ---------------- dense GEMM: W staged in LDS as fp16 (8 b128 reads/k, was 16) ----------------
// Yh[row] = (X[row]@W) * dinv[row], fp16 out. All W reads are wave-broadcast.
template <int K>
__global__ __launch_bounds__(256) void gemm64_kernel(const float* __restrict__ X,
                                                     const float* __restrict__ W,
                                                     const int* __restrict__ deg,
                                                     __half* __restrict__ Yh, int N) {
    __shared__ __half Wh[K * 64];              // 16 KB for K=128
    int t = threadIdx.x;
    for (int i = t; i < K * 16; i += 256) {    // stage + convert fp32 -> fp16
        float4 w4 = reinterpret_cast<const float4*>(W)[i];
        __half2* dst = reinterpret_cast<__half2*>(&Wh[i * 4]);
        dst[0] = __floats2half2_rn(w4.x, w4.y);
        dst[1] = __floats2half2_rn(w4.z, w4.w);
    }
    __syncthreads();
    int row = blockIdx.x * 256 + t;
    if (row >= N) return;
    float acc[64];
#pragma unroll
    for (int c = 0; c < 64; ++c) acc[c] = 0.0f;
    const float4* xr = reinterpret_cast<const float4*>(X + (size_t)row * K);
    for (int k4 = 0; k4 < K / 4; ++k4) {
        float4 xv = xr[k4];
#pragma unroll
        for (int kk = 0; kk < 4; ++kk) {
            float xs = (kk == 0) ? xv.x : (kk == 1) ? xv.y : (kk == 2) ? xv.z : xv.w;
            const float4* wr = reinterpret_cast<const float4*>(&Wh[(k4 * 4 + kk) * 64]);
#pragma unroll
            for (int c8 = 0; c8 < 8; ++c8) {
                float4 raw = wr[c8];           // 8 fp16 = 8 columns
                float2 f0 = __half22float2(*reinterpret_cast<__half2*>(&raw.x));
                float2 f1 = __half22float2(*reinterpret_cast<__half2*>(&raw.y));
                float2 f2 = __half22float2(*reinterpret_cast<__half2*>(&raw.z));
                float2 f3 = __half22float2(*reinterpret_cast<__half2*>(&raw.w));
                acc[c8 * 8 + 0] += xs * f0.x; acc[c8 * 8 + 1] += xs * f0.y;
                acc[c8 * 8 + 2] += xs * f1.x; acc[c8 * 8 + 3] += xs * f1.y;
                acc[c8 * 8 + 4] += xs * f2.x; acc[c8 * 8 + 5] += xs * f2.y;
                acc[c8 * 8 + 6] += xs * f3.x; acc[c8 * 8 + 7] += xs * f3.y;
            }
        }
    }
    float di = rsqrtf((float)deg[row] + 1.0f);
    __half2* yr = reinterpret_cast<__half2*>(Yh + (size_t)row * 64);
#pragma unroll
    for (int c2 = 0; c2 < 32; ++c2)
        yr[c2] = __floats2half2_rn(acc[2 * c2] * di, acc[2 * c2 + 1] * di);
}

// ---------------- per-node register gather, 16 rows in flight ----------------
__device__ __forceinline__ float gatherN(const __half* __restrict__ xwp,
                                         const int* __restrict__ er,
                                         int s0, int n, int lane) {
    float acc = 0.0f;
    int e = 0;
    for (; e + 16 <= n; e += 16) {
        int r[16]; float v[16];
#pragma unroll
        for (int k = 0; k < 16; ++k) r[k] = er[s0 + e + k];
#pragma unroll
        for (int k = 0; k < 16; ++k) v[k] = __half2float(xwp[((r[k] & 0xFFFF) << 6) + lane]);
#pragma unroll
        for (int k = 0; k < 16; ++k) acc += v[k];
    }
    if (e + 8 <= n) {
        int r[8]; float v[8];
#pragma unroll
        for (int k = 0; k < 8; ++k) r[k] = er[s0 + e + k];
#pragma unroll
        for (int k = 0; k < 8; ++k) v[k] = __half2float(xwp[((r[k] & 0xFFFF) << 6) + lane]);
#pragma unroll
        for (int k = 0; k < 8; ++k) acc += v[k];
        e += 8;
    }
    if (e + 4 <= n) {
        int r[4]; float v[4];
#pragma unroll
        for (int k = 0; k < 4; ++k) r[k] = er[s0 + e + k];
#pragma unroll
        for (int k = 0; k < 4; ++k) v[k] = __half2float(xwp[((r[k] & 0xFFFF) << 6) + lane]);
#pragma unroll
        for (int k = 0; k < 4; ++k) acc += v[k];
        e += 4;
    }
    for (; e < n; ++e)
        acc += __half2float(xwp[((er[s0 + e] & 0xFFFF) << 6) + lane]);
    return acc;
}

// ---------------- layer1: per-node agg + tanh + @W2, writes prescaled fp16 xw2 ----------------
__global__ __launch_bounds__(256) void aggA_kernel(
    const __half* __restrict__ xwp, const int* __restrict__ erec2,
    const int* __restrict__ nodeStart, const int* __restrict__ deg,
    const float* __restrict__ b1v, const float* __restrict__ W2,
    __half* __restrict__ xw2p) {
    __shared__ float W2l[64 * 64];             // 16 KB
    __shared__ float rowS[4][64];
    int t = threadIdx.x;
    for (int i = t; i < 1024; i += 256)
        reinterpret_cast<float4*>(W2l)[i] = reinterpret_cast<const float4*>(W2)[i];
    __syncthreads();
    int node = __builtin_amdgcn_readfirstlane(blockIdx.x * 4 + (t >> 6));
    if (node >= N_NODES) return;
    int lane = t & 63, wib = t >> 6;
    int s0 = __builtin_amdgcn_readfirstlane(nodeStart[node]);
    int n  = __builtin_amdgcn_readfirstlane(deg[node]);
    float acc = gatherN(xwp, erec2, s0, n, lane);
    float selfv = __half2float(xwp[(node << 6) + lane]);
    float di = rsqrtf((float)n + 1.0f);
    float h = tanhf((acc + selfv) * di + b1v[lane]);
    rowS[wib][lane] = h;                       // wave-private
    float o = 0.0f;
#pragma unroll
    for (int f4 = 0; f4 < 16; ++f4) {
        float4 rv = reinterpret_cast<const float4*>(&rowS[wib][0])[f4];
        o += rv.x * W2l[(f4 * 4 + 0) * 64 + lane];
        o += rv.y * W2l[(f4 * 4 + 1) * 64 + lane];
        o += rv.z * W2l[(f4 * 4 + 2) * 64 + lane];
        o += rv.w * W2l[(f4 * 4 + 3) * 64 + lane];
    }
    xw2p[(node << 6) + lane] = __float2half_rn(o * di);   // prescale for layer 2
}

// ---------------- layer2: per-node agg + emb + tanh + head + log_softmax ----------------
__global__ __launch_bounds__(256) void aggB_kernel(
    const __half* __restrict__ xw2p, const int* __restrict__ erec2,
    const int* __restrict__ nodeStart, const int* __restrict__ deg,
    const float* __restrict__ b2v, const float* __restrict__ Wc,
    const float* __restrict__ bc, float* __restrict__ embOut,
    float* __restrict__ logitsOut) {
    __shared__ float Wcl[64 * 32];             // 8 KB
    __shared__ float rowS[4][64];
    __shared__ float bcl[32];
    int t = threadIdx.x;
    for (int i = t; i < 512; i += 256)
        reinterpret_cast<float4*>(Wcl)[i] = reinterpret_cast<const float4*>(Wc)[i];
    if (t < 32) bcl[t] = bc[t];
    __syncthreads();
    int node = __builtin_amdgcn_readfirstlane(blockIdx.x * 4 + (t >> 6));
    if (node >= N_NODES) return;
    int lane = t & 63, wib = t >> 6;
    int s0 = __builtin_amdgcn_readfirstlane(nodeStart[node]);
    int n  = __builtin_amdgcn_readfirstlane(deg[node]);
    float acc = gatherN(xw2p, erec2, s0, n, lane);
    float selfv = __half2float(xw2p[(node << 6) + lane]);
    float di = rsqrtf((float)n + 1.0f);
    float v = (acc + selfv) * di + b2v[lane];
    embOut[(node << 6) + lane] = v;
    rowS[wib][lane] = tanhf(v);                // wave-private
    int j = lane & 31, half = lane >> 5;
    float p = half ? 0.0f : bcl[j];
#pragma unroll
    for (int f4 = 0; f4 < 8; ++f4) {
        float4 rv = reinterpret_cast<const float4*>(&rowS[wib][half * 32])[f4];
        int fb = half * 32 + f4 * 4;
        p += rv.x * Wcl[(fb + 0) * 32 + j];
        p += rv.y * Wcl[(fb + 1) * 32 + j];
        p += rv.z * Wcl[(fb + 2) * 32 + j];
        p += rv.w * Wcl[(fb + 3) * 32 + j];
    }
    p += __shfl_down(p, 32);                   // lanes 0..31 hold full logits
    float m = p;
#pragma unroll
    for (int o = 16; o > 0; o >>= 1) m = fmaxf(m, __shfl_xor(m, o, 32));
    float ex = __expf(p - m);
    float s = ex;
#pragma unroll
    for (int o = 16; o > 0; o >>= 1) s += __shfl_xor(s, o, 32);
    if (half == 0) logitsOut[node * 32 + j] = p - m - logf(s);
}

extern "C" void kernel_launch(void* const* d_in, const int* in_sizes, int n_in,
                              void* d_out, int out_size, void* d_ws, size_t ws_size,
                              hipStream_t stream) {
    const float* x   = (const float*)d_in[0];
    const int*   ei  = (const int*)d_in[1];
    const float* W1  = (const float*)d_in[2];
    const float* b1  = (const float*)d_in[3];
    const float* W2  = (const float*)d_in[4];
    const float* b2  = (const float*)d_in[5];
    const float* Wp1 = (const float*)d_in[6];
    const float* bp1 = (const float*)d_in[7];
    const float* Wp2 = (const float*)d_in[8];
    const float* bp2 = (const float*)d_in[9];

    char* ws = (char*)d_ws;
    int*    gcnt   = (int*)(ws + OFF_GCNT);
    int*    gbase  = (int*)(ws + OFF_GBASE);
    int*    deg    = (int*)(ws + OFF_DEG);
    int*    nstart = (int*)(ws + OFF_NSTART);
    int*    perblk = (int*)(ws + OFF_PERBLK);
    int*    erec   = (int*)(ws + OFF_EREC);
    int*    erec2  = (int*)(ws + OFF_EREC2);
    __half* xwp    = (__half*)(ws + OFF_XW);
    __half* xw2p   = (__half*)(ws + OFF_XW2);
    float*  Wc     = (float*)(ws + OFF_WC);
    float*  bc     = (float*)(ws + OFF_BC);

    float* emb_out    = (float*)d_out;                        // [N,64]
    float* logits_out = (float*)d_out + (size_t)N_NODES * 64; // [N,32]

    zero_kernel<<<1, 256, 0, stream>>>((int4*)(ws + OFF_GCNT));
    hist_kernel<<<NBLK_BIN, BIN_THREADS, 0, stream>>>(ei, gcnt, perblk);
    scanP_kernel<<<1, 1024, 0, stream>>>(gcnt, gbase, Wp1, bp1, Wp2, bp2, Wc, bc);
    scat_kernel<<<NBLK_BIN, BIN_THREADS, 0, stream>>>(ei, gbase, perblk, erec);
    sortK_kernel<<<NBUCK, 512, 0, stream>>>(erec, gbase, erec2, nstart, deg);

    gemm64_kernel<IN_DIM><<<(N_NODES + 255) / 256, 256, 0, stream>>>(x, W1, deg, xwp, N_NODES);
    aggA_kernel<<<(N_NODES + 3) / 4, 256, 0, stream>>>(xwp, erec2, nstart, deg, b1, W2, xw2p);
    aggB_kernel<<<(N_NODES + 3) / 4, 256, 0, stream>>>(xw2p, erec2, nstart, deg, b2, Wc, bc, emb_out, logits_out);
}

// Round 18
// 138.648 us; speedup vs baseline: 1.3630x; 1.0702x over previous
//
#include <hip/hip_runtime.h>
#include <hip/hip_fp16.h>

#define N_NODES 50000
#define N_EDGES 800000
#define IN_DIM 128
#define OUT_DIM 64
#define OUT_DATA 32

#define BUCKET_SHIFT 6
#define BUCKET_SIZE 64                                       // nodes per bucket
#define NBUCK ((N_NODES + BUCKET_SIZE - 1) / BUCKET_SIZE)    // 782
#define NBLK_BIN 128
#define BIN_THREADS 1024
#define EPB ((N_EDGES + NBLK_BIN - 1) / NBLK_BIN)            // 6250
#define ELCAP 1536                                           // bucket edge capacity (mean 1024)

// ---------------- workspace layout (bytes) ----------------
#define OFF_GCNT    0u          // int[NBUCK]       -> pad 4096  (zeroed)
#define OFF_GBASE   4096u       // int[NBUCK+1]     -> pad 4096
#define OFF_DEG     8192u       // int[50048]       -> pad 200704 (written by sortK)
#define OFF_NSTART  208896u     // int[50048]       -> pad 200704 (written by sortK)
#define OFF_PERBLK  409600u     // int[128*782]     -> pad 401408
#define OFF_EREC    811008u     // int[E] packed (local<<16)|src = 3.2 MB
#define OFF_EREC2   4012032u    // int[E] node-grouped           = 3.2 MB
#define OFF_XW      7213056u    // half[N*64] prescaled by dinv  = 6.4 MB
#define OFF_XW2     13613056u   // half[N*64] prescaled by dinv
#define OFF_WC      20013056u   // float[64*32]
#define OFF_BC      20021248u   // float[32]
// total ~20 MB

// Detect whether edge_index is stored as int64 (high dwords all zero) or int32.
__device__ __forceinline__ bool ei_is64(const int* ei) {
    int o = 0;
#pragma unroll
    for (int k = 0; k < 16; ++k) o |= ei[2 * k + 1];
    return o == 0;
}
__device__ __forceinline__ int load_ei(const int* ei, long long flat, bool is64) {
    return is64 ? (int)(((const long long*)ei)[flat]) : ei[flat];
}

// ---------------- zero gcnt (4096 B = 256 int4) ----------------
__global__ void zero_kernel(int4* __restrict__ p) {
    p[threadIdx.x] = make_int4(0, 0, 0, 0);
}

// ---------------- pass 1: bucket histogram (per-block LDS) ----------------
__global__ __launch_bounds__(BIN_THREADS) void hist_kernel(const int* __restrict__ ei,
                                                           int* __restrict__ gcnt,
                                                           int* __restrict__ perblk) {
    __shared__ int lh[NBUCK];
    int t = threadIdx.x;
    for (int i = t; i < NBUCK; i += BIN_THREADS) lh[i] = 0;
    __syncthreads();
    bool is64 = ei_is64(ei);
    int e0 = blockIdx.x * EPB;
    int e1 = e0 + EPB; if (e1 > N_EDGES) e1 = N_EDGES;
    for (int e = e0 + t; e < e1; e += BIN_THREADS) {
        int d = load_ei(ei, (long long)N_EDGES + e, is64);
        atomicAdd(&lh[d >> BUCKET_SHIFT], 1);
    }
    __syncthreads();
    for (int i = t; i < NBUCK; i += BIN_THREADS)
        perblk[blockIdx.x * NBUCK + i] = atomicAdd(&gcnt[i], lh[i]);
}

// ---------------- prefix over buckets; fused head-weight folding ----------------
__global__ __launch_bounds__(1024) void scanP_kernel(
    const int* __restrict__ gcnt, int* __restrict__ gbase,
    const float* __restrict__ Wp1, const float* __restrict__ bp1,
    const float* __restrict__ Wp2, const float* __restrict__ bp2,
    float* __restrict__ Wc, float* __restrict__ bc) {
    __shared__ int tmp[1024];
    int t = threadIdx.x;
    int v = (t < NBUCK) ? gcnt[t] : 0;
    tmp[t] = v;
    __syncthreads();
    for (int o = 1; o < 1024; o <<= 1) {
        int x = tmp[t];
        if (t >= o) x += tmp[t - o];
        __syncthreads();
        tmp[t] = x;
        __syncthreads();
    }
    if (t < NBUCK) gbase[t] = tmp[t] - v;
    if (t == NBUCK - 1) gbase[NBUCK] = tmp[t];
    // head fold: Wc = Wp1@Wp2, bc = bp1@Wp2+bp2
    for (int idx = t; idx < 64 * 32; idx += 1024) {
        int r = idx >> 5, j = idx & 31;
        float s = 0.0f;
        for (int k = 0; k < 64; ++k) s += Wp1[r * 64 + k] * Wp2[k * 32 + j];
        Wc[idx] = s;
    }
    if (t < 32) {
        float s = bp2[t];
        for (int k = 0; k < 64; ++k) s += bp1[k] * Wp2[k * 32 + t];
        bc[t] = s;
    }
}

// ---------------- pass 2: scatter packed records grouped by (block,bucket) ----------------
__global__ __launch_bounds__(BIN_THREADS) void scat_kernel(const int* __restrict__ ei,
                                                           const int* __restrict__ gbase,
                                                           const int* __restrict__ perblk,
                                                           int* __restrict__ erec) {
    __shared__ int lh[NBUCK];
    __shared__ int base[NBUCK];
    int t = threadIdx.x;
    for (int i = t; i < NBUCK; i += BIN_THREADS) {
        lh[i] = 0;
        base[i] = gbase[i] + perblk[blockIdx.x * NBUCK + i];
    }
    __syncthreads();
    bool is64 = ei_is64(ei);
    int e0 = blockIdx.x * EPB;
    int e1 = e0 + EPB; if (e1 > N_EDGES) e1 = N_EDGES;
    for (int e = e0 + t; e < e1; e += BIN_THREADS) {
        int s = load_ei(ei, e, is64);
        int d = load_ei(ei, (long long)N_EDGES + e, is64);
        int b = d >> BUCKET_SHIFT;
        int slot = atomicAdd(&lh[b], 1);
        erec[base[b] + slot] = s | ((d & (BUCKET_SIZE - 1)) << 16);  // s<65536, local<64
    }
}

// ---------------- one-time in-bucket counting sort: erec -> node-grouped erec2 ----------------
__global__ __launch_bounds__(512) void sortK_kernel(const int* __restrict__ erec,
                                                    const int* __restrict__ gbase,
                                                    int* __restrict__ erec2,
                                                    int* __restrict__ nodeStart,
                                                    int* __restrict__ deg) {
    __shared__ int elist[ELCAP];
    __shared__ int lcntS[64];
    __shared__ int startS[65];
    int t = threadIdx.x;
    int ebeg = gbase[blockIdx.x], eend = gbase[blockIdx.x + 1];
    int ecnt = eend - ebeg; if (ecnt > ELCAP) ecnt = ELCAP;
    for (int i = t; i < ecnt; i += 512) elist[i] = erec[ebeg + i];
    if (t < 64) lcntS[t] = 0;
    __syncthreads();
    int rec0 = -1, rank0 = 0, rec1 = -1, rank1 = 0, rec2 = -1, rank2 = 0;
    { int i = t;        if (i < ecnt) { rec0 = elist[i]; rank0 = atomicAdd(&lcntS[rec0 >> 16], 1); } }
    { int i = t + 512;  if (i < ecnt) { rec1 = elist[i]; rank1 = atomicAdd(&lcntS[rec1 >> 16], 1); } }
    { int i = t + 1024; if (i < ecnt) { rec2 = elist[i]; rank2 = atomicAdd(&lcntS[rec2 >> 16], 1); } }
    __syncthreads();
    if (t < 64) {
        int vcnt = lcntS[t]; int sum = vcnt;
        for (int off = 1; off < 64; off <<= 1) {
            int o = __shfl_up(sum, off, 64);
            if (t >= off) sum += o;
        }
        startS[t + 1] = sum; if (t == 0) startS[0] = 0;
    }
    __syncthreads();
    if (rec0 >= 0) erec2[ebeg + startS[rec0 >> 16] + rank0] = rec0;
    if (rec1 >= 0) erec2[ebeg + startS[rec1 >> 16] + rank1] = rec1;
    if (rec2 >= 0) erec2[ebeg + startS[rec2 >> 16] + rank2] = rec2;
    if (t < 64) {
        int node = (blockIdx.x << BUCKET_SHIFT) + t;
        nodeStart[node] = ebeg + startS[t];
        deg[node] = startS[t + 1] - startS[t];
    }
}

// ---------------- dense GEMM: 4 threads/row (16 cols each), W fp16 in LDS ----------------
// 3125 waves (~12/CU) so the 2 b128/k wave-broadcast reads run at LDS throughput.
// Yh[row] = (X[row]@W) * dinv[row], fp16 out.
template <int K>
__global__ __launch_bounds__(256) void gemm64_kernel(const float* __restrict__ X,
                                                     const float* __restrict__ W,
                                                     const int* __restrict__ deg,
                                                     __half* __restrict__ Yh, int N) {
    __shared__ __half Wh[K * 64];              // 16 KB for K=128
    int t = threadIdx.x;
    for (int i = t; i < K * 16; i += 256) {    // stage + convert fp32 -> fp16
        float4 w4 = reinterpret_cast<const float4*>(W)[i];
        __half2* dst = reinterpret_cast<__half2*>(&Wh[i * 4]);
        dst[0] = __floats2half2_rn(w4.x, w4.y);
        dst[1] = __floats2half2_rn(w4.z, w4.w);
    }
    __syncthreads();
    int row = blockIdx.x * 64 + (t >> 2);      // 64 rows per block
    if (row >= N) return;
    int cg = t & 3;                            // col group: cols [cg*16, cg*16+16)
    float acc[16];
#pragma unroll
    for (int c = 0; c < 16; ++c) acc[c] = 0.0f;
    const float4* xr = reinterpret_cast<const float4*>(X + (size_t)row * K);
    for (int k4 = 0; k4 < K / 4; ++k4) {
        float4 xv = xr[k4];
#pragma unroll
        for (int kk = 0; kk < 4; ++kk) {
            float xs = (kk == 0) ? xv.x : (kk == 1) ? xv.y : (kk == 2) ? xv.z : xv.w;
            const float4* wr = reinterpret_cast<const float4*>(&Wh[(k4 * 4 + kk) * 64 + cg * 16]);
            float4 raw0 = wr[0];               // 8 fp16 = cols cg*16 + 0..7
            float4 raw1 = wr[1];               // 8 fp16 = cols cg*16 + 8..15
            float2 f0 = __half22float2(*reinterpret_cast<__half2*>(&raw0.x));
            float2 f1 = __half22float2(*reinterpret_cast<__half2*>(&raw0.y));
            float2 f2 = __half22float2(*reinterpret_cast<__half2*>(&raw0.z));
            float2 f3 = __half22float2(*reinterpret_cast<__half2*>(&raw0.w));
            float2 f4 = __half22float2(*reinterpret_cast<__half2*>(&raw1.x));
            float2 f5 = __half22float2(*reinterpret_cast<__half2*>(&raw1.y));
            float2 f6 = __half22float2(*reinterpret_cast<__half2*>(&raw1.z));
            float2 f7 = __half22float2(*reinterpret_cast<__half2*>(&raw1.w));
            acc[0]  += xs * f0.x; acc[1]  += xs * f0.y;
            acc[2]  += xs * f1.x; acc[3]  += xs * f1.y;
            acc[4]  += xs * f2.x; acc[5]  += xs * f2.y;
            acc[6]  += xs * f3.x; acc[7]  += xs * f3.y;
            acc[8]  += xs * f4.x; acc[9]  += xs * f4.y;
            acc[10] += xs * f5.x; acc[11] += xs * f5.y;
            acc[12] += xs * f6.x; acc[13] += xs * f6.y;
            acc[14] += xs * f7.x; acc[15] += xs * f7.y;
        }
    }
    float di = rsqrtf((float)deg[row] + 1.0f);
    __half2* yr = reinterpret_cast<__half2*>(Yh + (size_t)row * 64 + cg * 16);
#pragma unroll
    for (int c2 = 0; c2 < 8; ++c2)
        yr[c2] = __floats2half2_rn(acc[2 * c2] * di, acc[2 * c2 + 1] * di);
}

// ---------------- per-node register gather, 16 rows in flight ----------------
__device__ __forceinline__ float gatherN(const __half* __restrict__ xwp,
                                         const int* __restrict__ er,
                                         int s0, int n, int lane) {
    float acc = 0.0f;
    int e = 0;
    for (; e + 16 <= n; e += 16) {
        int r[16]; float v[16];
#pragma unroll
        for (int k = 0; k < 16; ++k) r[k] = er[s0 + e + k];
#pragma unroll
        for (int k = 0; k < 16; ++k) v[k] = __half2float(xwp[((r[k] & 0xFFFF) << 6) + lane]);
#pragma unroll
        for (int k = 0; k < 16; ++k) acc += v[k];
    }
    if (e + 8 <= n) {
        int r[8]; float v[8];
#pragma unroll
        for (int k = 0; k < 8; ++k) r[k] = er[s0 + e + k];
#pragma unroll
        for (int k = 0; k < 8; ++k) v[k] = __half2float(xwp[((r[k] & 0xFFFF) << 6) + lane]);
#pragma unroll
        for (int k = 0; k < 8; ++k) acc += v[k];
        e += 8;
    }
    if (e + 4 <= n) {
        int r[4]; float v[4];
#pragma unroll
        for (int k = 0; k < 4; ++k) r[k] = er[s0 + e + k];
#pragma unroll
        for (int k = 0; k < 4; ++k) v[k] = __half2float(xwp[((r[k] & 0xFFFF) << 6) + lane]);
#pragma unroll
        for (int k = 0; k < 4; ++k) acc += v[k];
        e += 4;
    }
    for (; e < n; ++e)
        acc += __half2float(xwp[((er[s0 + e] & 0xFFFF) << 6) + lane]);
    return acc;
}

// ---------------- layer1: per-node agg + tanh + @W2, writes prescaled fp16 xw2 ----------------
__global__ __launch_bounds__(256) void aggA_kernel(
    const __half* __restrict__ xwp, const int* __restrict__ erec2,
    const int* __restrict__ nodeStart, const int* __restrict__ deg,
    const float* __restrict__ b1v, const float* __restrict__ W2,
    __half* __restrict__ xw2p) {
    __shared__ float W2l[64 * 64];             // 16 KB
    __shared__ float rowS[4][64];
    int t = threadIdx.x;
    for (int i = t; i < 1024; i += 256)
        reinterpret_cast<float4*>(W2l)[i] = reinterpret_cast<const float4*>(W2)[i];
    __syncthreads();
    int node = __builtin_amdgcn_readfirstlane(blockIdx.x * 4 + (t >> 6));
    if (node >= N_NODES) return;
    int lane = t & 63, wib = t >> 6;
    int s0 = __builtin_amdgcn_readfirstlane(nodeStart[node]);
    int n  = __builtin_amdgcn_readfirstlane(deg[node]);
    float acc = gatherN(xwp, erec2, s0, n, lane);
    float selfv = __half2float(xwp[(node << 6) + lane]);
    float di = rsqrtf((float)n + 1.0f);
    float h = tanhf((acc + selfv) * di + b1v[lane]);
    rowS[wib][lane] = h;                       // wave-private
    float o = 0.0f;
#pragma unroll
    for (int f4 = 0; f4 < 16; ++f4) {
        float4 rv = reinterpret_cast<const float4*>(&rowS[wib][0])[f4];
        o += rv.x * W2l[(f4 * 4 + 0) * 64 + lane];
        o += rv.y * W2l[(f4 * 4 + 1) * 64 + lane];
        o += rv.z * W2l[(f4 * 4 + 2) * 64 + lane];
        o += rv.w * W2l[(f4 * 4 + 3) * 64 + lane];
    }
    xw2p[(node << 6) + lane] = __float2half_rn(o * di);   // prescale for layer 2
}

// ---------------- layer2: per-node agg + emb + tanh + head + log_softmax ----------------
__global__ __launch_bounds__(256) void aggB_kernel(
    const __half* __restrict__ xw2p, const int* __restrict__ erec2,
    const int* __restrict__ nodeStart, const int* __restrict__ deg,
    const float* __restrict__ b2v, const float* __restrict__ Wc,
    const float* __restrict__ bc, float* __restrict__ embOut,
    float* __restrict__ logitsOut) {
    __shared__ float Wcl[64 * 32];             // 8 KB
    __shared__ float rowS[4][64];
    __shared__ float bcl[32];
    int t = threadIdx.x;
    for (int i = t; i < 512; i += 256)
        reinterpret_cast<float4*>(Wcl)[i] = reinterpret_cast<const float4*>(Wc)[i];
    if (t < 32) bcl[t] = bc[t];
    __syncthreads();
    int node = __builtin_amdgcn_readfirstlane(blockIdx.x * 4 + (t >> 6));
    if (node >= N_NODES) return;
    int lane = t & 63, wib = t >> 6;
    int s0 = __builtin_amdgcn_readfirstlane(nodeStart[node]);
    int n  = __builtin_amdgcn_readfirstlane(deg[node]);
    float acc = gatherN(xw2p, erec2, s0, n, lane);
    float selfv = __half2float(xw2p[(node << 6) + lane]);
    float di = rsqrtf((float)n + 1.0f);
    float v = (acc + selfv) * di + b2v[lane];
    embOut[(node << 6) + lane] = v;
    rowS[wib][lane] = tanhf(v);                // wave-private
    int j = lane & 31, half = lane >> 5;
    float p = half ? 0.0f : bcl[j];
#pragma unroll
    for (int f4 = 0; f4 < 8; ++f4) {
        float4 rv = reinterpret_cast<const float4*>(&rowS[wib][half * 32])[f4];
        int fb = half * 32 + f4 * 4;
        p += rv.x * Wcl[(fb + 0) * 32 + j];
        p += rv.y * Wcl[(fb + 1) * 32 + j];
        p += rv.z * Wcl[(fb + 2) * 32 + j];
        p += rv.w * Wcl[(fb + 3) * 32 + j];
    }
    p += __shfl_down(p, 32);                   // lanes 0..31 hold full logits
    float m = p;
#pragma unroll
    for (int o = 16; o > 0; o >>= 1) m = fmaxf(m, __shfl_xor(m, o, 32));
    float ex = __expf(p - m);
    float s = ex;
#pragma unroll
    for (int o = 16; o > 0; o >>= 1) s += __shfl_xor(s, o, 32);
    if (half == 0) logitsOut[node * 32 + j] = p - m - logf(s);
}

extern "C" void kernel_launch(void* const* d_in, const int* in_sizes, int n_in,
                              void* d_out, int out_size, void* d_ws, size_t ws_size,
                              hipStream_t stream) {
    const float* x   = (const float*)d_in[0];
    const int*   ei  = (const int*)d_in[1];
    const float* W1  = (const float*)d_in[2];
    const float* b1  = (const float*)d_in[3];
    const float* W2  = (const float*)d_in[4];
    const float* b2  = (const float*)d_in[5];
    const float* Wp1 = (const float*)d_in[6];
    const float* bp1 = (const float*)d_in[7];
    const float* Wp2 = (const float*)d_in[8];
    const float* bp2 = (const float*)d_in[9];

    char* ws = (char*)d_ws;
    int*    gcnt   = (int*)(ws + OFF_GCNT);
    int*    gbase  = (int*)(ws + OFF_GBASE);
    int*    deg    = (int*)(ws + OFF_DEG);
    int*    nstart = (int*)(ws + OFF_NSTART);
    int*    perblk = (int*)(ws + OFF_PERBLK);
    int*    erec   = (int*)(ws + OFF_EREC);
    int*    erec2  = (int*)(ws + OFF_EREC2);
    __half* xwp    = (__half*)(ws + OFF_XW);
    __half* xw2p   = (__half*)(ws + OFF_XW2);
    float*  Wc     = (float*)(ws + OFF_WC);
    float*  bc     = (float*)(ws + OFF_BC);

    float* emb_out    = (float*)d_out;                        // [N,64]
    float* logits_out = (float*)d_out + (size_t)N_NODES * 64; // [N,32]

    zero_kernel<<<1, 256, 0, stream>>>((int4*)(ws + OFF_GCNT));
    hist_kernel<<<NBLK_BIN, BIN_THREADS, 0, stream>>>(ei, gcnt, perblk);
    scanP_kernel<<<1, 1024, 0, stream>>>(gcnt, gbase, Wp1, bp1, Wp2, bp2, Wc, bc);
    scat_kernel<<<NBLK_BIN, BIN_THREADS, 0, stream>>>(ei, gbase, perblk, erec);
    sortK_kernel<<<NBUCK, 512, 0, stream>>>(erec, gbase, erec2, nstart, deg);

    gemm64_kernel<IN_DIM><<<(N_NODES * 4 + 255) / 256, 256, 0, stream>>>(x, W1, deg, xwp, N_NODES);
    aggA_kernel<<<(N_NODES + 3) / 4, 256, 0, stream>>>(xwp, erec2, nstart, deg, b1, W2, xw2p);
    aggB_kernel<<<(N_NODES + 3) / 4, 256, 0, stream>>>(xw2p, erec2, nstart, deg, b2, Wc, bc, emb_out, logits_out);
}